// Round 5
// baseline (741.109 us; speedup 1.0000x reference)
//
#include <hip/hip_runtime.h>
#include <hip/hip_bf16.h>
#include <math.h>

#define N_    100000
#define E_    1600000
#define ETOT_ 1700000   // E + N self-loops
#define G_    64
#define H_    128
#define GH_   8192      // G_*H_
#define L_    3
#define GD_   32
#define NEG_  0.2f
#define EPS_  1e-5f

#define NBUK_ 391       // ceil(N_/256) buckets of 256 dst nodes
#define CH_   2048      // edges per chunk
#define MCH_  782       // ceil(E_/CH_)

typedef unsigned short ushort_t;
typedef unsigned int uint_t;
typedef __attribute__((ext_vector_type(4))) float f32x4;
typedef __attribute__((ext_vector_type(8))) short bf16x8;
typedef __attribute__((ext_vector_type(8))) unsigned short ushort8;

__device__ __forceinline__ ushort_t bfb(float f) {
    __hip_bfloat16 h = __float2bfloat16(f);
    return *reinterpret_cast<ushort_t*>(&h);
}
__device__ __forceinline__ float uf(ushort_t u) {
    return __uint_as_float(((uint_t)u) << 16);
}

// ---------------- init: zero accumulators, graph starts ----------------

__global__ void k_init(float* pooled, float* gsum, float* gsq, int* gstart,
                       const int* __restrict__ batch) {
    int i = blockIdx.x * 256 + threadIdx.x;
    if (i < L_ * GH_) { pooled[i] = 0.f; gsum[i] = 0.f; gsq[i] = 0.f; }
    if (i <= G_) {
        int lo = 0, hi = N_;
        while (lo < hi) { int mid = (lo + hi) >> 1; if (batch[mid] < i) lo = mid + 1; else hi = mid; }
        gstart[i] = lo;
    }
}

// ---------------- bucketed CSR build (no global atomics) ----------------

__global__ __launch_bounds__(256) void k_bcount(const int* __restrict__ edst, int* __restrict__ C) {
    __shared__ int hist[NBUK_];
    int t = threadIdx.x, m = blockIdx.x;
    for (int i = t; i < NBUK_; i += 256) hist[i] = 0;
    __syncthreads();
    int base = m * CH_;
#pragma unroll
    for (int j = 0; j < CH_ / 256; j++) {
        int e = base + j * 256 + t;
        if (e < E_) atomicAdd(&hist[edst[e] >> 8], 1);
    }
    __syncthreads();
    for (int i = t; i < NBUK_; i += 256) C[i * MCH_ + m] = hist[i];
}

// per-bucket exclusive scan over chunks; bucketEdges[b] = total
__global__ __launch_bounds__(1024) void k_bscan(int* __restrict__ C, int* __restrict__ bucketEdges) {
    __shared__ int arr[1024];
    int b = blockIdx.x, t = threadIdx.x;
    int v = (t < MCH_) ? C[b * MCH_ + t] : 0;
    arr[t] = v;
    __syncthreads();
    for (int off = 1; off < 1024; off <<= 1) {
        int x = (t >= off) ? arr[t - off] : 0;
        __syncthreads();
        arr[t] += x;
        __syncthreads();
    }
    if (t < MCH_) C[b * MCH_ + t] = arr[t] - v;
    if (t == 1023) bucketEdges[b] = arr[1023];
}

// scan over buckets: bstartE (edges only), bstartT (edges + self-loops)
__global__ __launch_bounds__(512) void k_bscan2(const int* __restrict__ bucketEdges,
                                                int* __restrict__ bstartE, int* __restrict__ bstartT,
                                                int* __restrict__ rowptr) {
    __shared__ int aE[512], aT[512];
    int t = threadIdx.x;
    int e = 0, tot = 0;
    if (t < NBUK_) {
        e = bucketEdges[t];
        int nib = N_ - t * 256; if (nib > 256) nib = 256;
        tot = e + nib;
    }
    aE[t] = e; aT[t] = tot;
    __syncthreads();
    for (int off = 1; off < 512; off <<= 1) {
        int xe = (t >= off) ? aE[t - off] : 0;
        int xt = (t >= off) ? aT[t - off] : 0;
        __syncthreads();
        aE[t] += xe; aT[t] += xt;
        __syncthreads();
    }
    if (t < NBUK_) { bstartE[t] = aE[t] - e; bstartT[t] = aT[t] - tot; }
    if (t == 0) rowptr[N_] = ETOT_;
}

// stage (src,dst) pairs bucket-contiguously
__global__ __launch_bounds__(256) void k_bscatter(const int* __restrict__ esrc, const int* __restrict__ edst,
                                                  const int* __restrict__ C, const int* __restrict__ bstartE,
                                                  int2* __restrict__ stag) {
    __shared__ int cur[NBUK_];
    int t = threadIdx.x, m = blockIdx.x;
    for (int i = t; i < NBUK_; i += 256) cur[i] = C[i * MCH_ + m] + bstartE[i];
    __syncthreads();
    int base = m * CH_;
#pragma unroll
    for (int j = 0; j < CH_ / 256; j++) {
        int e = base + j * 256 + t;
        if (e < E_) {
            int s = esrc[e], d = edst[e];
            int pos = atomicAdd(&cur[d >> 8], 1);
            int2 p; p.x = s; p.y = d;
            stag[pos] = p;
        }
    }
}

// per-bucket: degree hist (+self-loop), scan -> rowptr, scatter -> colarr
__global__ __launch_bounds__(256) void k_bfinal(const int2* __restrict__ stag,
                                                const int* __restrict__ bucketEdges,
                                                const int* __restrict__ bstartE, const int* __restrict__ bstartT,
                                                int* __restrict__ rowptr, int* __restrict__ colarr) {
    __shared__ int deg[256];
    __shared__ int cursor[256];
    int b = blockIdx.x, t = threadIdx.x;
    int nb0 = b * 256;
    int nib = N_ - nb0; if (nib > 256) nib = 256;
    int ebeg = bstartE[b], ecnt = bucketEdges[b];
    deg[t] = (t < nib) ? 1 : 0;
    __syncthreads();
    for (int i = t; i < ecnt; i += 256) {
        int2 p = stag[ebeg + i];
        atomicAdd(&deg[p.y - nb0], 1);
    }
    __syncthreads();
    int v = deg[t];
    cursor[t] = v;
    __syncthreads();
    for (int off = 1; off < 256; off <<= 1) {
        int x = (t >= off) ? cursor[t - off] : 0;
        __syncthreads();
        cursor[t] += x;
        __syncthreads();
    }
    int excl = cursor[t] - v;
    int rowbase = bstartT[b];
    if (t < nib) {
        rowptr[nb0 + t] = rowbase + excl;
        colarr[rowbase + excl] = nb0 + t;   // self-loop first
    }
    __syncthreads();
    cursor[t] = excl + 1;
    __syncthreads();
    for (int i = t; i < ecnt; i += 256) {
        int2 p = stag[ebeg + i];
        int pos = atomicAdd(&cursor[p.y - nb0], 1);
        colarr[rowbase + pos] = p.x;
    }
}

// ---------------- Wt prep: Wt[l][c][k] = bf16( c<128 ? Ws[l][k][c] : Wd[l][k][c-128] ) ----------------

__global__ void k_prep_w(const float* __restrict__ Ws, const float* __restrict__ Wd,
                         ushort_t* __restrict__ Wt) {
    int i = blockIdx.x * 256 + threadIdx.x;
    if (i >= L_ * 256 * H_) return;
    int l = i >> 15;
    int r = i & 32767;
    int c = r >> 7, k = r & 127;
    float v = (c < H_) ? Ws[(size_t)l * H_ * H_ + k * H_ + c]
                       : Wd[(size_t)l * H_ * H_ + k * H_ + (c - H_)];
    Wt[i] = bfb(v);
}

// ---------------- MFMA GEMM with fused input norm ----------------
// FIRST=1: A = bf16(x0[f32]).  FIRST=0: A = bf16(relu((h - mv[g])*iv[g] + bb)).
// Outputs xlb, xrb both bf16 [N,128].

template<int FIRST>
__global__ __launch_bounds__(256) void k_mfma_t(const float* __restrict__ x0,
                                                const ushort_t* __restrict__ hin,
                                                const int* __restrict__ batch,
                                                const float* __restrict__ mv,
                                                const float* __restrict__ iv,
                                                const float* __restrict__ bb,
                                                const ushort_t* __restrict__ Wt,
                                                ushort_t* __restrict__ xlb,
                                                ushort_t* __restrict__ xrb) {
    int wv = threadIdx.x >> 6, lane = threadIdx.x & 63;
    int row0 = (blockIdx.x * 4 + wv) * 16;
    if (row0 >= N_) return;
    int sl = lane & 15, q = lane >> 4;
    int row = row0 + sl;

    bf16x8 a[4];
    if (FIRST) {
        const float* ap = x0 + (size_t)row * H_ + q * 8;
#pragma unroll
        for (int kk = 0; kk < 4; kk++) {
            float4 v0 = *(const float4*)(ap + kk * 32);
            float4 v1 = *(const float4*)(ap + kk * 32 + 4);
            bf16x8 t;
            t[0] = (short)bfb(v0.x); t[1] = (short)bfb(v0.y);
            t[2] = (short)bfb(v0.z); t[3] = (short)bfb(v0.w);
            t[4] = (short)bfb(v1.x); t[5] = (short)bfb(v1.y);
            t[6] = (short)bfb(v1.z); t[7] = (short)bfb(v1.w);
            a[kk] = t;
        }
    } else {
        int g = batch[row];
        const ushort_t* hp = hin + (size_t)row * H_ + q * 8;
        const float* mvp = mv + g * H_ + q * 8;
        const float* ivp = iv + g * H_ + q * 8;
        const float* bbp = bb + q * 8;
#pragma unroll
        for (int kk = 0; kk < 4; kk++) {
            ushort8 u = *(const ushort8*)(hp + kk * 32);
            float4 m0 = *(const float4*)(mvp + kk * 32);
            float4 m1 = *(const float4*)(mvp + kk * 32 + 4);
            float4 i0 = *(const float4*)(ivp + kk * 32);
            float4 i1 = *(const float4*)(ivp + kk * 32 + 4);
            float4 c0 = *(const float4*)(bbp + kk * 32);
            float4 c1 = *(const float4*)(bbp + kk * 32 + 4);
            bf16x8 t;
            t[0] = (short)bfb(fmaxf((uf(u[0]) - m0.x) * i0.x + c0.x, 0.f));
            t[1] = (short)bfb(fmaxf((uf(u[1]) - m0.y) * i0.y + c0.y, 0.f));
            t[2] = (short)bfb(fmaxf((uf(u[2]) - m0.z) * i0.z + c0.z, 0.f));
            t[3] = (short)bfb(fmaxf((uf(u[3]) - m0.w) * i0.w + c0.w, 0.f));
            t[4] = (short)bfb(fmaxf((uf(u[4]) - m1.x) * i1.x + c1.x, 0.f));
            t[5] = (short)bfb(fmaxf((uf(u[5]) - m1.y) * i1.y + c1.y, 0.f));
            t[6] = (short)bfb(fmaxf((uf(u[6]) - m1.z) * i1.z + c1.z, 0.f));
            t[7] = (short)bfb(fmaxf((uf(u[7]) - m1.w) * i1.w + c1.w, 0.f));
            a[kk] = t;
        }
    }

    f32x4 acc[16];
#pragma unroll
    for (int c = 0; c < 16; c++) acc[c] = (f32x4){0.f, 0.f, 0.f, 0.f};

#pragma unroll
    for (int c = 0; c < 16; c++) {
        const ushort_t* bp = Wt + (size_t)(c * 16 + sl) * H_ + q * 8;
#pragma unroll
        for (int kk = 0; kk < 4; kk++) {
            bf16x8 b = *(const bf16x8*)(bp + kk * 32);
            acc[c] = __builtin_amdgcn_mfma_f32_16x16x32_bf16(a[kk], b, acc[c], 0, 0, 0);
        }
    }

    int orow = row0 + q * 4;
#pragma unroll
    for (int c = 0; c < 8; c++)
#pragma unroll
        for (int j = 0; j < 4; j++)
            xlb[(size_t)(orow + j) * H_ + c * 16 + sl] = bfb(acc[c][j]);
#pragma unroll
    for (int c = 8; c < 16; c++)
#pragma unroll
        for (int j = 0; j < 4; j++)
            xrb[(size_t)(orow + j) * H_ + (c - 8) * 16 + sl] = bfb(acc[c][j]);
}

// ---------------- GATv2 conv + fused GraphNorm stats ----------------
// 16 lanes x 8 dims per dst row; no-max softmax; h written bf16; block-level
// stat reduction (batch-sorted rows) -> global atomics.

__global__ __launch_bounds__(256) void k_conv(const ushort_t* __restrict__ xlb,
                                              const ushort_t* __restrict__ xrb,
                                              const int* __restrict__ rowptr, const int* __restrict__ colarr,
                                              const float* __restrict__ attl, const float* __restrict__ bcl,
                                              const int* __restrict__ batch,
                                              ushort_t* __restrict__ h,
                                              float* __restrict__ gsum, float* __restrict__ gsq) {
    __shared__ float ls1[H_], ls2[H_];
    int tid = threadIdx.x;
    if (tid < H_) { ls1[tid] = 0.f; ls2[tid] = 0.f; }
    __syncthreads();

    int lane = tid & 63, wv = tid >> 6;
    int sl = lane & 15, q = lane >> 4;
    int row = blockIdx.x * 16 + wv * 4 + q;
    int d0 = sl * 8;

    float xrv[8], av[8], av5[8];
    {
        ushort8 ux = *(const ushort8*)(xrb + (size_t)row * H_ + d0);
        float4 a0 = *(const float4*)(attl + d0);
        float4 a1 = *(const float4*)(attl + d0 + 4);
        av[0] = a0.x; av[1] = a0.y; av[2] = a0.z; av[3] = a0.w;
        av[4] = a1.x; av[5] = a1.y; av[6] = a1.z; av[7] = a1.w;
#pragma unroll
        for (int e = 0; e < 8; e++) { xrv[e] = uf(ux[e]); av5[e] = NEG_ * av[e]; }
    }

    int jb = rowptr[row];
    int n = rowptr[row + 1] - jb;

    float ssum = 0.f;
    float ac[8] = {0.f, 0.f, 0.f, 0.f, 0.f, 0.f, 0.f, 0.f};

    int s = (n > 0) ? colarr[jb] : 0;
    for (int i = 0; i < n; i++) {
        int snext = (i + 1 < n) ? colarr[jb + i + 1] : 0;
        ushort8 u = *(const ushort8*)(xlb + (size_t)s * H_ + d0);
        float v[8];
        float p = 0.f;
#pragma unroll
        for (int e = 0; e < 8; e++) {
            v[e] = uf(u[e]);
            float t = v[e] + xrv[e];
            p = fmaf(t, (t > 0.f ? av[e] : av5[e]), p);
        }
        p += __shfl_xor(p, 8);
        p += __shfl_xor(p, 4);
        p += __shfl_xor(p, 2);
        p += __shfl_xor(p, 1);
        float wgt = __expf(p);
        ssum += wgt;
#pragma unroll
        for (int e = 0; e < 8; e++) ac[e] = fmaf(wgt, v[e], ac[e]);
        s = snext;
    }

    float inv = 1.f / ssum;
    float4 b0 = *(const float4*)(bcl + d0);
    float4 b1 = *(const float4*)(bcl + d0 + 4);
    float o[8];
    o[0] = ac[0] * inv + b0.x; o[1] = ac[1] * inv + b0.y;
    o[2] = ac[2] * inv + b0.z; o[3] = ac[3] * inv + b0.w;
    o[4] = ac[4] * inv + b1.x; o[5] = ac[5] * inv + b1.y;
    o[6] = ac[6] * inv + b1.z; o[7] = ac[7] * inv + b1.w;

    ushort8 ho;
#pragma unroll
    for (int e = 0; e < 8; e++) ho[e] = bfb(o[e]);
    *(ushort8*)(h + (size_t)row * H_ + d0) = ho;

    // fused GraphNorm stats
    float s1[8], s2[8];
#pragma unroll
    for (int e = 0; e < 8; e++) { s1[e] = o[e]; s2[e] = o[e] * o[e]; }

    int g0 = batch[blockIdx.x * 16];
    int g1 = batch[blockIdx.x * 16 + 15];
    if (g0 == g1) {
#pragma unroll
        for (int e = 0; e < 8; e++) {
            s1[e] += __shfl_xor(s1[e], 16); s1[e] += __shfl_xor(s1[e], 32);
            s2[e] += __shfl_xor(s2[e], 16); s2[e] += __shfl_xor(s2[e], 32);
        }
        if (q == 0) {
#pragma unroll
            for (int e = 0; e < 8; e++) {
                atomicAdd(&ls1[d0 + e], s1[e]);
                atomicAdd(&ls2[d0 + e], s2[e]);
            }
        }
        __syncthreads();
        if (tid < H_) atomicAdd(&gsum[g0 * H_ + tid], ls1[tid]);
        else if (tid < 2 * H_) atomicAdd(&gsq[g0 * H_ + tid - H_], ls2[tid - H_]);
    } else {
        int g = batch[row];
#pragma unroll
        for (int e = 0; e < 8; e++) {
            atomicAdd(&gsum[g * H_ + d0 + e], s1[e]);
            atomicAdd(&gsq[g * H_ + d0 + e], s2[e]);
        }
    }
}

// ---------------- GraphNorm finalize: gsum -> mv = ms*mean, gsq -> iv = gn_w*rsqrt(var+eps) ----------------

__global__ void k_gn_fin(float* gsum, float* gsq, const int* __restrict__ gstart,
                         const float* __restrict__ gnwl, const float* __restrict__ gnmsl) {
    int i = blockIdx.x * 256 + threadIdx.x;
    if (i < GH_) {
        int g = i >> 7, d = i & 127;
        int c = gstart[g + 1] - gstart[g]; if (c < 1) c = 1;
        float ic = 1.f / (float)c;
        float mean = gsum[i] * ic;
        float e2   = gsq[i] * ic;
        float ms = gnmsl[d];
        float var = e2 - ms * (2.f - ms) * mean * mean;
        gsum[i] = ms * mean;
        gsq[i]  = gnwl[d] * rsqrtf(var + EPS_);
    }
}

// ---------------- pooled_l = segment-sum of relu(norm(h)) ----------------

__global__ void k_pool(const ushort_t* __restrict__ h, const int* __restrict__ batch,
                       const float* __restrict__ mv, const float* __restrict__ iv,
                       const float* __restrict__ bb, float* __restrict__ pooled_l) {
    int tid = threadIdx.x;
    int nb = blockIdx.x * 64;
    int d2 = (tid & 63) * 2, hh = tid >> 6;
    int nend = nb + 64; if (nend > N_) nend = N_;
    float b0 = bb[d2], b1 = bb[d2 + 1];
    float p0 = 0.f, p1 = 0.f; int curg = -1;
    float m0 = 0.f, m1 = 0.f, i0 = 0.f, i1 = 0.f;
    for (int n = nb + hh; n < nend; n += 4) {
        int g = batch[n];
        if (g != curg) {
            if (curg >= 0) {
                atomicAdd(&pooled_l[curg * H_ + d2], p0);
                atomicAdd(&pooled_l[curg * H_ + d2 + 1], p1);
            }
            p0 = 0.f; p1 = 0.f; curg = g;
            m0 = mv[g * H_ + d2]; m1 = mv[g * H_ + d2 + 1];
            i0 = iv[g * H_ + d2]; i1 = iv[g * H_ + d2 + 1];
        }
        uint_t u = *(const uint_t*)(h + (size_t)n * H_ + d2);
        float v0 = __uint_as_float(u << 16);
        float v1 = __uint_as_float(u & 0xffff0000u);
        v0 = fmaxf((v0 - m0) * i0 + b0, 0.f);
        v1 = fmaxf((v1 - m1) * i1 + b1, 0.f);
        p0 += v0; p1 += v1;
    }
    if (curg >= 0) {
        atomicAdd(&pooled_l[curg * H_ + d2], p0);
        atomicAdd(&pooled_l[curg * H_ + d2 + 1], p1);
    }
}

// ---------------- final MLP ----------------

__global__ __launch_bounds__(128) void k_mlp(const float* __restrict__ pooled, const float* __restrict__ gfeat,
                                             const int* __restrict__ gstart,
                                             const float* __restrict__ W1, const float* __restrict__ b1,
                                             const float* __restrict__ W2, const float* __restrict__ b2,
                                             float* __restrict__ out) {
    int g = blockIdx.x;
    int c = threadIdx.x;
    __shared__ float hc[H_ * L_ + GD_];
    __shared__ float zz[H_];
    int cn = gstart[g + 1] - gstart[g]; if (cn < 1) cn = 1;
    float ic = 1.f / (float)cn;
    for (int k = c; k < H_ * L_; k += 128)
        hc[k] = pooled[(k >> 7) * GH_ + g * H_ + (k & 127)] * ic;
    if (c < GD_) hc[H_ * L_ + c] = gfeat[g * GD_ + c];
    __syncthreads();
    float z = b1[c];
#pragma unroll 4
    for (int k = 0; k < H_ * L_ + GD_; k++)
        z += hc[k] * W1[k * H_ + c];
    z = fmaxf(z, 0.f);
    zz[c] = z * W2[c];
    __syncthreads();
    for (int off = 64; off > 0; off >>= 1) {
        if (c < off) zz[c] += zz[c + off];
        __syncthreads();
    }
    if (c == 0) out[g] = zz[0] + b2[0];
}

// ---------------- launch ----------------

extern "C" void kernel_launch(void* const* d_in, const int* in_sizes, int n_in,
                              void* d_out, int out_size, void* d_ws, size_t ws_size,
                              hipStream_t stream) {
    const float* x0    = (const float*)d_in[0];
    const float* gfeat = (const float*)d_in[1];
    const float* Wsrc  = (const float*)d_in[2];
    const float* Wdst  = (const float*)d_in[3];
    const float* att   = (const float*)d_in[4];
    const float* bconv = (const float*)d_in[5];
    const float* gnw   = (const float*)d_in[6];
    const float* gnb   = (const float*)d_in[7];
    const float* gnms  = (const float*)d_in[8];
    const float* W1    = (const float*)d_in[9];
    const float* b1    = (const float*)d_in[10];
    const float* W2    = (const float*)d_in[11];
    const float* b2    = (const float*)d_in[12];
    const int*   eidx  = (const int*)d_in[13];
    const int*   batch = (const int*)d_in[14];
    const int* esrc = eidx;
    const int* edst = eidx + E_;
    float* out = (float*)d_out;

    char* w = (char*)d_ws;
    size_t off = 0;
    auto alloc = [&](size_t bytes) { char* p = w + off; off += (bytes + 255) & ~(size_t)255; return p; };
    ushort_t* xlb  = (ushort_t*)alloc((size_t)N_ * H_ * 2);
    ushort_t* xrb  = (ushort_t*)alloc((size_t)N_ * H_ * 2);
    ushort_t* h    = (ushort_t*)alloc((size_t)N_ * H_ * 2);
    ushort_t* Wt   = (ushort_t*)alloc((size_t)L_ * 256 * H_ * 2);
    int*   rowptr  = (int*)alloc((size_t)(N_ + 1) * 4);
    int*   colarr  = (int*)alloc((size_t)ETOT_ * 4);
    int*   bktE    = (int*)alloc(NBUK_ * 4);
    int*   bstartE = (int*)alloc(NBUK_ * 4);
    int*   bstartT = (int*)alloc(NBUK_ * 4);
    int*   gstart  = (int*)alloc((G_ + 1) * 4);
    float* gsum    = (float*)alloc((size_t)L_ * GH_ * 4);
    float* gsq     = (float*)alloc((size_t)L_ * GH_ * 4);
    float* pooled  = (float*)alloc((size_t)L_ * GH_ * 4);
    // aliases: used only during CSR build, before xlb/xrb are first written
    int2* stag = (int2*)xlb;            // E_*8B = 12.8MB <= 25.6MB
    int*  C    = (int*)xrb;             // NBUK_*MCH_*4B = 1.2MB <= 25.6MB
    (void)ws_size; (void)in_sizes; (void)n_in; (void)out_size;

    k_init<<<(N_ + 255) / 256, 256, 0, stream>>>(pooled, gsum, gsq, gstart, batch);
    k_bcount<<<MCH_, 256, 0, stream>>>(edst, C);
    k_bscan<<<NBUK_, 1024, 0, stream>>>(C, bktE);
    k_bscan2<<<1, 512, 0, stream>>>(bktE, bstartE, bstartT, rowptr);
    k_bscatter<<<MCH_, 256, 0, stream>>>(esrc, edst, C, bstartE, stag);
    k_bfinal<<<NBUK_, 256, 0, stream>>>(stag, bktE, bstartE, bstartT, rowptr, colarr);
    k_prep_w<<<(L_ * 256 * H_ + 255) / 256, 256, 0, stream>>>(Wsrc, Wdst, Wt);

    int mfma_grid = (N_ / 16 + 3) / 4;
    for (int l = 0; l < L_; l++) {
        if (l == 0)
            k_mfma_t<1><<<mfma_grid, 256, 0, stream>>>(x0, h, batch, gsum, gsq, gnb,
                                                       Wt, xlb, xrb);
        else
            k_mfma_t<0><<<mfma_grid, 256, 0, stream>>>(x0, h, batch,
                                                       gsum + (size_t)(l - 1) * GH_,
                                                       gsq + (size_t)(l - 1) * GH_,
                                                       gnb + (size_t)(l - 1) * H_,
                                                       Wt + (size_t)l * 256 * H_, xlb, xrb);
        k_conv<<<N_ / 16, 256, 0, stream>>>(xlb, xrb, rowptr, colarr,
                                            att + (size_t)l * H_, bconv + (size_t)l * H_,
                                            batch, h,
                                            gsum + (size_t)l * GH_, gsq + (size_t)l * GH_);
        k_gn_fin<<<GH_ / 256, 256, 0, stream>>>(gsum + (size_t)l * GH_, gsq + (size_t)l * GH_,
                                                gstart, gnw + (size_t)l * H_, gnms + (size_t)l * H_);
        k_pool<<<(N_ + 63) / 64, 256, 0, stream>>>(h, batch,
                                                   gsum + (size_t)l * GH_, gsq + (size_t)l * GH_,
                                                   gnb + (size_t)l * H_, pooled + (size_t)l * GH_);
    }

    k_mlp<<<G_, 128, 0, stream>>>(pooled, gfeat, gstart, W1, b1, W2, b2, out);
}

// Round 6
// 630.589 us; speedup vs baseline: 1.1753x; 1.1753x over previous
//
#include <hip/hip_runtime.h>
#include <hip/hip_bf16.h>
#include <math.h>

#define N_    100000
#define E_    1600000
#define ETOT_ 1700000   // E + N self-loops
#define G_    64
#define H_    128
#define GH_   8192      // G_*H_
#define L_    3
#define GD_   32
#define NEG_  0.2f
#define EPS_  1e-5f

#define NBUK_ 391       // ceil(N_/256) buckets of 256 dst nodes
#define CH_   2048      // edges per chunk
#define MCH_  782       // ceil(E_/CH_)

typedef unsigned short ushort_t;
typedef unsigned int uint_t;
typedef __attribute__((ext_vector_type(4))) float f32x4;
typedef __attribute__((ext_vector_type(8))) short bf16x8;
typedef __attribute__((ext_vector_type(8))) unsigned short ushort8;

__device__ __forceinline__ ushort_t bfb(float f) {
    __hip_bfloat16 h = __float2bfloat16(f);
    return *reinterpret_cast<ushort_t*>(&h);
}
__device__ __forceinline__ float uf(ushort_t u) {
    return __uint_as_float(((uint_t)u) << 16);
}

// ---------------- init: zero accumulators, graph starts ----------------

__global__ void k_init(float* pooled, float* gsum, float* gsq, int* gstart,
                       const int* __restrict__ batch) {
    int i = blockIdx.x * 256 + threadIdx.x;
    if (i < L_ * GH_) { pooled[i] = 0.f; gsum[i] = 0.f; gsq[i] = 0.f; }
    if (i <= G_) {
        int lo = 0, hi = N_;
        while (lo < hi) { int mid = (lo + hi) >> 1; if (batch[mid] < i) lo = mid + 1; else hi = mid; }
        gstart[i] = lo;
    }
}

// ---------------- bucketed CSR build (no global atomics) ----------------

__global__ __launch_bounds__(256) void k_bcount(const int* __restrict__ edst, int* __restrict__ C) {
    __shared__ int hist[NBUK_];
    int t = threadIdx.x, m = blockIdx.x;
    for (int i = t; i < NBUK_; i += 256) hist[i] = 0;
    __syncthreads();
    int base = m * CH_;
#pragma unroll
    for (int j = 0; j < CH_ / 256; j++) {
        int e = base + j * 256 + t;
        if (e < E_) atomicAdd(&hist[edst[e] >> 8], 1);
    }
    __syncthreads();
    for (int i = t; i < NBUK_; i += 256) C[i * MCH_ + m] = hist[i];
}

// per-bucket exclusive scan over chunks; bucketEdges[b] = total
__global__ __launch_bounds__(1024) void k_bscan(int* __restrict__ C, int* __restrict__ bucketEdges) {
    __shared__ int arr[1024];
    int b = blockIdx.x, t = threadIdx.x;
    int v = (t < MCH_) ? C[b * MCH_ + t] : 0;
    arr[t] = v;
    __syncthreads();
    for (int off = 1; off < 1024; off <<= 1) {
        int x = (t >= off) ? arr[t - off] : 0;
        __syncthreads();
        arr[t] += x;
        __syncthreads();
    }
    if (t < MCH_) C[b * MCH_ + t] = arr[t] - v;
    if (t == 1023) bucketEdges[b] = arr[1023];
}

// scan over buckets: bstartE (edges only), bstartT (edges + self-loops)
__global__ __launch_bounds__(512) void k_bscan2(const int* __restrict__ bucketEdges,
                                                int* __restrict__ bstartE, int* __restrict__ bstartT,
                                                int* __restrict__ rowptr) {
    __shared__ int aE[512], aT[512];
    int t = threadIdx.x;
    int e = 0, tot = 0;
    if (t < NBUK_) {
        e = bucketEdges[t];
        int nib = N_ - t * 256; if (nib > 256) nib = 256;
        tot = e + nib;
    }
    aE[t] = e; aT[t] = tot;
    __syncthreads();
    for (int off = 1; off < 512; off <<= 1) {
        int xe = (t >= off) ? aE[t - off] : 0;
        int xt = (t >= off) ? aT[t - off] : 0;
        __syncthreads();
        aE[t] += xe; aT[t] += xt;
        __syncthreads();
    }
    if (t < NBUK_) { bstartE[t] = aE[t] - e; bstartT[t] = aT[t] - tot; }
    if (t == 0) rowptr[N_] = ETOT_;
}

// stage (src,dst) pairs bucket-contiguously
__global__ __launch_bounds__(256) void k_bscatter(const int* __restrict__ esrc, const int* __restrict__ edst,
                                                  const int* __restrict__ C, const int* __restrict__ bstartE,
                                                  int2* __restrict__ stag) {
    __shared__ int cur[NBUK_];
    int t = threadIdx.x, m = blockIdx.x;
    for (int i = t; i < NBUK_; i += 256) cur[i] = C[i * MCH_ + m] + bstartE[i];
    __syncthreads();
    int base = m * CH_;
#pragma unroll
    for (int j = 0; j < CH_ / 256; j++) {
        int e = base + j * 256 + t;
        if (e < E_) {
            int s = esrc[e], d = edst[e];
            int pos = atomicAdd(&cur[d >> 8], 1);
            int2 p; p.x = s; p.y = d;
            stag[pos] = p;
        }
    }
}

// per-bucket: degree hist (+self-loop), scan -> rowptr, scatter -> colarr
__global__ __launch_bounds__(256) void k_bfinal(const int2* __restrict__ stag,
                                                const int* __restrict__ bucketEdges,
                                                const int* __restrict__ bstartE, const int* __restrict__ bstartT,
                                                int* __restrict__ rowptr, int* __restrict__ colarr) {
    __shared__ int deg[256];
    __shared__ int cursor[256];
    int b = blockIdx.x, t = threadIdx.x;
    int nb0 = b * 256;
    int nib = N_ - nb0; if (nib > 256) nib = 256;
    int ebeg = bstartE[b], ecnt = bucketEdges[b];
    deg[t] = (t < nib) ? 1 : 0;
    __syncthreads();
    for (int i = t; i < ecnt; i += 256) {
        int2 p = stag[ebeg + i];
        atomicAdd(&deg[p.y - nb0], 1);
    }
    __syncthreads();
    int v = deg[t];
    cursor[t] = v;
    __syncthreads();
    for (int off = 1; off < 256; off <<= 1) {
        int x = (t >= off) ? cursor[t - off] : 0;
        __syncthreads();
        cursor[t] += x;
        __syncthreads();
    }
    int excl = cursor[t] - v;
    int rowbase = bstartT[b];
    if (t < nib) {
        rowptr[nb0 + t] = rowbase + excl;
        colarr[rowbase + excl] = nb0 + t;   // self-loop first
    }
    __syncthreads();
    cursor[t] = excl + 1;
    __syncthreads();
    for (int i = t; i < ecnt; i += 256) {
        int2 p = stag[ebeg + i];
        int pos = atomicAdd(&cursor[p.y - nb0], 1);
        colarr[rowbase + pos] = p.x;
    }
}

// ---------------- Wt prep: Wt[l][c][k] = bf16( c<128 ? Ws[l][k][c] : Wd[l][k][c-128] ) ----------------

__global__ void k_prep_w(const float* __restrict__ Ws, const float* __restrict__ Wd,
                         ushort_t* __restrict__ Wt) {
    int i = blockIdx.x * 256 + threadIdx.x;
    if (i >= L_ * 256 * H_) return;
    int l = i >> 15;
    int r = i & 32767;
    int c = r >> 7, k = r & 127;
    float v = (c < H_) ? Ws[(size_t)l * H_ * H_ + k * H_ + c]
                       : Wd[(size_t)l * H_ * H_ + k * H_ + (c - H_)];
    Wt[i] = bfb(v);
}

// ---------------- MFMA GEMM with fused input norm ----------------
// FIRST=1: A = bf16(x0[f32]).  FIRST=0: A = bf16(relu((h - mv[g])*iv[g] + bb)).

template<int FIRST>
__global__ __launch_bounds__(256) void k_mfma_t(const float* __restrict__ x0,
                                                const ushort_t* __restrict__ hin,
                                                const int* __restrict__ batch,
                                                const float* __restrict__ mv,
                                                const float* __restrict__ iv,
                                                const float* __restrict__ bb,
                                                const ushort_t* __restrict__ Wt,
                                                ushort_t* __restrict__ xlb,
                                                ushort_t* __restrict__ xrb) {
    int wv = threadIdx.x >> 6, lane = threadIdx.x & 63;
    int row0 = (blockIdx.x * 4 + wv) * 16;
    if (row0 >= N_) return;
    int sl = lane & 15, q = lane >> 4;
    int row = row0 + sl;

    bf16x8 a[4];
    if (FIRST) {
        const float* ap = x0 + (size_t)row * H_ + q * 8;
#pragma unroll
        for (int kk = 0; kk < 4; kk++) {
            float4 v0 = *(const float4*)(ap + kk * 32);
            float4 v1 = *(const float4*)(ap + kk * 32 + 4);
            bf16x8 t;
            t[0] = (short)bfb(v0.x); t[1] = (short)bfb(v0.y);
            t[2] = (short)bfb(v0.z); t[3] = (short)bfb(v0.w);
            t[4] = (short)bfb(v1.x); t[5] = (short)bfb(v1.y);
            t[6] = (short)bfb(v1.z); t[7] = (short)bfb(v1.w);
            a[kk] = t;
        }
    } else {
        int g = batch[row];
        const ushort_t* hp = hin + (size_t)row * H_ + q * 8;
        const float* mvp = mv + g * H_ + q * 8;
        const float* ivp = iv + g * H_ + q * 8;
        const float* bbp = bb + q * 8;
#pragma unroll
        for (int kk = 0; kk < 4; kk++) {
            ushort8 u = *(const ushort8*)(hp + kk * 32);
            float4 m0 = *(const float4*)(mvp + kk * 32);
            float4 m1 = *(const float4*)(mvp + kk * 32 + 4);
            float4 i0 = *(const float4*)(ivp + kk * 32);
            float4 i1 = *(const float4*)(ivp + kk * 32 + 4);
            float4 c0 = *(const float4*)(bbp + kk * 32);
            float4 c1 = *(const float4*)(bbp + kk * 32 + 4);
            bf16x8 t;
            t[0] = (short)bfb(fmaxf((uf(u[0]) - m0.x) * i0.x + c0.x, 0.f));
            t[1] = (short)bfb(fmaxf((uf(u[1]) - m0.y) * i0.y + c0.y, 0.f));
            t[2] = (short)bfb(fmaxf((uf(u[2]) - m0.z) * i0.z + c0.z, 0.f));
            t[3] = (short)bfb(fmaxf((uf(u[3]) - m0.w) * i0.w + c0.w, 0.f));
            t[4] = (short)bfb(fmaxf((uf(u[4]) - m1.x) * i1.x + c1.x, 0.f));
            t[5] = (short)bfb(fmaxf((uf(u[5]) - m1.y) * i1.y + c1.y, 0.f));
            t[6] = (short)bfb(fmaxf((uf(u[6]) - m1.z) * i1.z + c1.z, 0.f));
            t[7] = (short)bfb(fmaxf((uf(u[7]) - m1.w) * i1.w + c1.w, 0.f));
            a[kk] = t;
        }
    }

    f32x4 acc[16];
#pragma unroll
    for (int c = 0; c < 16; c++) acc[c] = (f32x4){0.f, 0.f, 0.f, 0.f};

#pragma unroll
    for (int c = 0; c < 16; c++) {
        const ushort_t* bp = Wt + (size_t)(c * 16 + sl) * H_ + q * 8;
#pragma unroll
        for (int kk = 0; kk < 4; kk++) {
            bf16x8 b = *(const bf16x8*)(bp + kk * 32);
            acc[c] = __builtin_amdgcn_mfma_f32_16x16x32_bf16(a[kk], b, acc[c], 0, 0, 0);
        }
    }

    int orow = row0 + q * 4;
#pragma unroll
    for (int c = 0; c < 8; c++)
#pragma unroll
        for (int j = 0; j < 4; j++)
            xlb[(size_t)(orow + j) * H_ + c * 16 + sl] = bfb(acc[c][j]);
#pragma unroll
    for (int c = 8; c < 16; c++)
#pragma unroll
        for (int j = 0; j < 4; j++)
            xrb[(size_t)(orow + j) * H_ + (c - 8) * 16 + sl] = bfb(acc[c][j]);
}

// ---------------- GATv2 conv: 16 lanes x 8 dims per dst row, no-max softmax ----------------
// barrier-free; 3-deep index / 2-deep row-data prefetch pipeline.

__global__ __launch_bounds__(256) void k_conv(const ushort_t* __restrict__ xlb,
                                              const ushort_t* __restrict__ xrb,
                                              const int* __restrict__ rowptr, const int* __restrict__ colarr,
                                              const float* __restrict__ attl, const float* __restrict__ bcl,
                                              ushort_t* __restrict__ h) {
    int tid = threadIdx.x;
    int lane = tid & 63, wv = tid >> 6;
    int sl = lane & 15, q = lane >> 4;
    int row = blockIdx.x * 16 + wv * 4 + q;
    int d0 = sl * 8;

    float xrv[8], av[8], av5[8];
    {
        ushort8 ux = *(const ushort8*)(xrb + (size_t)row * H_ + d0);
        float4 a0 = *(const float4*)(attl + d0);
        float4 a1 = *(const float4*)(attl + d0 + 4);
        av[0] = a0.x; av[1] = a0.y; av[2] = a0.z; av[3] = a0.w;
        av[4] = a1.x; av[5] = a1.y; av[6] = a1.z; av[7] = a1.w;
#pragma unroll
        for (int e = 0; e < 8; e++) { xrv[e] = uf(ux[e]); av5[e] = NEG_ * av[e]; }
    }

    int jb = rowptr[row];
    int n = rowptr[row + 1] - jb;   // n >= 1 (self-loop)
    int last = n - 1;

    float ssum = 0.f;
    float ac[8] = {0.f, 0.f, 0.f, 0.f, 0.f, 0.f, 0.f, 0.f};

    int c0 = colarr[jb];
    int c1 = colarr[jb + (1 < last ? 1 : last)];
    int sc = colarr[jb + (2 < last ? 2 : last)];
    ushort8 u0 = *(const ushort8*)(xlb + (size_t)c0 * H_ + d0);
    ushort8 u1 = *(const ushort8*)(xlb + (size_t)c1 * H_ + d0);

    for (int i = 0; i < n; i++) {
        int i3 = i + 3; if (i3 > last) i3 = last;
        int cn = colarr[jb + i3];
        ushort8 u2 = *(const ushort8*)(xlb + (size_t)sc * H_ + d0);

        float v[8];
        float p = 0.f;
#pragma unroll
        for (int e = 0; e < 8; e++) {
            v[e] = uf(u0[e]);
            float t = v[e] + xrv[e];
            p = fmaf(t, (t > 0.f ? av[e] : av5[e]), p);
        }
        p += __shfl_xor(p, 8);
        p += __shfl_xor(p, 4);
        p += __shfl_xor(p, 2);
        p += __shfl_xor(p, 1);
        float wgt = __expf(p);
        ssum += wgt;
#pragma unroll
        for (int e = 0; e < 8; e++) ac[e] = fmaf(wgt, v[e], ac[e]);

        u0 = u1; u1 = u2; sc = cn;
    }

    float inv = 1.f / ssum;
    float4 b0 = *(const float4*)(bcl + d0);
    float4 b1 = *(const float4*)(bcl + d0 + 4);
    ushort8 ho;
    ho[0] = bfb(ac[0] * inv + b0.x); ho[1] = bfb(ac[1] * inv + b0.y);
    ho[2] = bfb(ac[2] * inv + b0.z); ho[3] = bfb(ac[3] * inv + b0.w);
    ho[4] = bfb(ac[4] * inv + b1.x); ho[5] = bfb(ac[5] * inv + b1.y);
    ho[6] = bfb(ac[6] * inv + b1.z); ho[7] = bfb(ac[7] * inv + b1.w);
    *(ushort8*)(h + (size_t)row * H_ + d0) = ho;
}

// ---------------- GraphNorm stats over bf16 h: run-length + boundary atomics ----------------

__global__ void k_gn_stat(const ushort_t* __restrict__ h, const int* __restrict__ batch,
                          float* gsum, float* gsq) {
    int tid = threadIdx.x;
    int nb = blockIdx.x * 64;
    int d2 = (tid & 63) * 2, hh = tid >> 6;
    int nend = nb + 64; if (nend > N_) nend = N_;
    float s10 = 0.f, s11 = 0.f, s20 = 0.f, s21 = 0.f; int curg = -1;
    for (int n = nb + hh; n < nend; n += 4) {
        int g = batch[n];
        if (g != curg) {
            if (curg >= 0) {
                atomicAdd(&gsum[curg * H_ + d2], s10);
                atomicAdd(&gsum[curg * H_ + d2 + 1], s11);
                atomicAdd(&gsq[curg * H_ + d2], s20);
                atomicAdd(&gsq[curg * H_ + d2 + 1], s21);
            }
            s10 = s11 = s20 = s21 = 0.f; curg = g;
        }
        uint_t u = *(const uint_t*)(h + (size_t)n * H_ + d2);
        float v0 = __uint_as_float(u << 16);
        float v1 = __uint_as_float(u & 0xffff0000u);
        s10 += v0; s11 += v1; s20 += v0 * v0; s21 += v1 * v1;
    }
    if (curg >= 0) {
        atomicAdd(&gsum[curg * H_ + d2], s10);
        atomicAdd(&gsum[curg * H_ + d2 + 1], s11);
        atomicAdd(&gsq[curg * H_ + d2], s20);
        atomicAdd(&gsq[curg * H_ + d2 + 1], s21);
    }
}

// ---------------- GraphNorm finalize: gsum -> mv = ms*mean, gsq -> iv = gn_w*rsqrt(var+eps) ----------------

__global__ void k_gn_fin(float* gsum, float* gsq, const int* __restrict__ gstart,
                         const float* __restrict__ gnwl, const float* __restrict__ gnmsl) {
    int i = blockIdx.x * 256 + threadIdx.x;
    if (i < GH_) {
        int g = i >> 7, d = i & 127;
        int c = gstart[g + 1] - gstart[g]; if (c < 1) c = 1;
        float ic = 1.f / (float)c;
        float mean = gsum[i] * ic;
        float e2   = gsq[i] * ic;
        float ms = gnmsl[d];
        float var = e2 - ms * (2.f - ms) * mean * mean;
        gsum[i] = ms * mean;
        gsq[i]  = gnwl[d] * rsqrtf(var + EPS_);
    }
}

// ---------------- pooled_l = segment-sum of relu(norm(h)) ----------------

__global__ void k_pool(const ushort_t* __restrict__ h, const int* __restrict__ batch,
                       const float* __restrict__ mv, const float* __restrict__ iv,
                       const float* __restrict__ bb, float* __restrict__ pooled_l) {
    int tid = threadIdx.x;
    int nb = blockIdx.x * 64;
    int d2 = (tid & 63) * 2, hh = tid >> 6;
    int nend = nb + 64; if (nend > N_) nend = N_;
    float b0 = bb[d2], b1 = bb[d2 + 1];
    float p0 = 0.f, p1 = 0.f; int curg = -1;
    float m0 = 0.f, m1 = 0.f, i0 = 0.f, i1 = 0.f;
    for (int n = nb + hh; n < nend; n += 4) {
        int g = batch[n];
        if (g != curg) {
            if (curg >= 0) {
                atomicAdd(&pooled_l[curg * H_ + d2], p0);
                atomicAdd(&pooled_l[curg * H_ + d2 + 1], p1);
            }
            p0 = 0.f; p1 = 0.f; curg = g;
            m0 = mv[g * H_ + d2]; m1 = mv[g * H_ + d2 + 1];
            i0 = iv[g * H_ + d2]; i1 = iv[g * H_ + d2 + 1];
        }
        uint_t u = *(const uint_t*)(h + (size_t)n * H_ + d2);
        float v0 = __uint_as_float(u << 16);
        float v1 = __uint_as_float(u & 0xffff0000u);
        v0 = fmaxf((v0 - m0) * i0 + b0, 0.f);
        v1 = fmaxf((v1 - m1) * i1 + b1, 0.f);
        p0 += v0; p1 += v1;
    }
    if (curg >= 0) {
        atomicAdd(&pooled_l[curg * H_ + d2], p0);
        atomicAdd(&pooled_l[curg * H_ + d2 + 1], p1);
    }
}

// ---------------- final MLP ----------------

__global__ __launch_bounds__(128) void k_mlp(const float* __restrict__ pooled, const float* __restrict__ gfeat,
                                             const int* __restrict__ gstart,
                                             const float* __restrict__ W1, const float* __restrict__ b1,
                                             const float* __restrict__ W2, const float* __restrict__ b2,
                                             float* __restrict__ out) {
    int g = blockIdx.x;
    int c = threadIdx.x;
    __shared__ float hc[H_ * L_ + GD_];
    __shared__ float zz[H_];
    int cn = gstart[g + 1] - gstart[g]; if (cn < 1) cn = 1;
    float ic = 1.f / (float)cn;
    for (int k = c; k < H_ * L_; k += 128)
        hc[k] = pooled[(k >> 7) * GH_ + g * H_ + (k & 127)] * ic;
    if (c < GD_) hc[H_ * L_ + c] = gfeat[g * GD_ + c];
    __syncthreads();
    float z = b1[c];
#pragma unroll 4
    for (int k = 0; k < H_ * L_ + GD_; k++)
        z += hc[k] * W1[k * H_ + c];
    z = fmaxf(z, 0.f);
    zz[c] = z * W2[c];
    __syncthreads();
    for (int off = 64; off > 0; off >>= 1) {
        if (c < off) zz[c] += zz[c + off];
        __syncthreads();
    }
    if (c == 0) out[g] = zz[0] + b2[0];
}

// ---------------- launch ----------------

extern "C" void kernel_launch(void* const* d_in, const int* in_sizes, int n_in,
                              void* d_out, int out_size, void* d_ws, size_t ws_size,
                              hipStream_t stream) {
    const float* x0    = (const float*)d_in[0];
    const float* gfeat = (const float*)d_in[1];
    const float* Wsrc  = (const float*)d_in[2];
    const float* Wdst  = (const float*)d_in[3];
    const float* att   = (const float*)d_in[4];
    const float* bconv = (const float*)d_in[5];
    const float* gnw   = (const float*)d_in[6];
    const float* gnb   = (const float*)d_in[7];
    const float* gnms  = (const float*)d_in[8];
    const float* W1    = (const float*)d_in[9];
    const float* b1    = (const float*)d_in[10];
    const float* W2    = (const float*)d_in[11];
    const float* b2    = (const float*)d_in[12];
    const int*   eidx  = (const int*)d_in[13];
    const int*   batch = (const int*)d_in[14];
    const int* esrc = eidx;
    const int* edst = eidx + E_;
    float* out = (float*)d_out;

    char* w = (char*)d_ws;
    size_t off = 0;
    auto alloc = [&](size_t bytes) { char* p = w + off; off += (bytes + 255) & ~(size_t)255; return p; };
    ushort_t* xlb  = (ushort_t*)alloc((size_t)N_ * H_ * 2);
    ushort_t* xrb  = (ushort_t*)alloc((size_t)N_ * H_ * 2);
    ushort_t* h    = (ushort_t*)alloc((size_t)N_ * H_ * 2);
    ushort_t* Wt   = (ushort_t*)alloc((size_t)L_ * 256 * H_ * 2);
    int*   rowptr  = (int*)alloc((size_t)(N_ + 1) * 4);
    int*   colarr  = (int*)alloc((size_t)ETOT_ * 4);
    int*   bktE    = (int*)alloc(NBUK_ * 4);
    int*   bstartE = (int*)alloc(NBUK_ * 4);
    int*   bstartT = (int*)alloc(NBUK_ * 4);
    int*   gstart  = (int*)alloc((G_ + 1) * 4);
    float* gsum    = (float*)alloc((size_t)L_ * GH_ * 4);
    float* gsq     = (float*)alloc((size_t)L_ * GH_ * 4);
    float* pooled  = (float*)alloc((size_t)L_ * GH_ * 4);
    // aliases: used only during CSR build, before xlb/xrb are first written
    int2* stag = (int2*)xlb;            // E_*8B = 12.8MB <= 25.6MB
    int*  C    = (int*)xrb;             // NBUK_*MCH_*4B = 1.2MB <= 25.6MB
    (void)ws_size; (void)in_sizes; (void)n_in; (void)out_size;

    k_init<<<(N_ + 255) / 256, 256, 0, stream>>>(pooled, gsum, gsq, gstart, batch);
    k_bcount<<<MCH_, 256, 0, stream>>>(edst, C);
    k_bscan<<<NBUK_, 1024, 0, stream>>>(C, bktE);
    k_bscan2<<<1, 512, 0, stream>>>(bktE, bstartE, bstartT, rowptr);
    k_bscatter<<<MCH_, 256, 0, stream>>>(esrc, edst, C, bstartE, stag);
    k_bfinal<<<NBUK_, 256, 0, stream>>>(stag, bktE, bstartE, bstartT, rowptr, colarr);
    k_prep_w<<<(L_ * 256 * H_ + 255) / 256, 256, 0, stream>>>(Wsrc, Wdst, Wt);

    int mfma_grid = (N_ / 16 + 3) / 4;
    for (int l = 0; l < L_; l++) {
        if (l == 0)
            k_mfma_t<1><<<mfma_grid, 256, 0, stream>>>(x0, h, batch, gsum, gsq, gnb,
                                                       Wt, xlb, xrb);
        else
            k_mfma_t<0><<<mfma_grid, 256, 0, stream>>>(x0, h, batch,
                                                       gsum + (size_t)(l - 1) * GH_,
                                                       gsq + (size_t)(l - 1) * GH_,
                                                       gnb + (size_t)(l - 1) * H_,
                                                       Wt + (size_t)l * 256 * H_, xlb, xrb);
        k_conv<<<N_ / 16, 256, 0, stream>>>(xlb, xrb, rowptr, colarr,
                                            att + (size_t)l * H_, bconv + (size_t)l * H_, h);
        k_gn_stat<<<(N_ + 63) / 64, 256, 0, stream>>>(h, batch,
                                                      gsum + (size_t)l * GH_, gsq + (size_t)l * GH_);
        k_gn_fin<<<GH_ / 256, 256, 0, stream>>>(gsum + (size_t)l * GH_, gsq + (size_t)l * GH_,
                                                gstart, gnw + (size_t)l * H_, gnms + (size_t)l * H_);
        k_pool<<<(N_ + 63) / 64, 256, 0, stream>>>(h, batch,
                                                   gsum + (size_t)l * GH_, gsq + (size_t)l * GH_,
                                                   gnb + (size_t)l * H_, pooled + (size_t)l * GH_);
    }

    k_mlp<<<G_, 128, 0, stream>>>(pooled, gfeat, gstart, W1, b1, W2, b2, out);
}